// Round 1
// baseline (817.727 us; speedup 1.0000x reference)
//
#include <hip/hip_runtime.h>

#define CRF_B 256
#define CRF_S 1024
#define CRF_T 128

// ---------------------------------------------------------------------------
// Kernel 1: all tag-gather terms of the gold score, negated into out.
//   -( start[tag0] + sum_t em[t,tag_t]*m_t + sum_{t>=1} trans[tag_{t-1},tag_t]*m_t
//      + end[tag_{S-1}]*m_{S-1} ) / B
// (the -sum_t log-softmax denominator part of gold is fused into kernel 2)
// ---------------------------------------------------------------------------
__global__ __launch_bounds__(256) void crf_gold_kernel(
    const float* __restrict__ em, const int* __restrict__ tags,
    const float* __restrict__ mask, const float* __restrict__ startT,
    const float* __restrict__ endT, const float* __restrict__ trans,
    float* __restrict__ out)
{
    const int b = blockIdx.x;
    const int tid = threadIdx.x;
    const int* tg = tags + (size_t)b * CRF_S;
    const float* mk = mask + (size_t)b * CRF_S;
    float acc = 0.f;
#pragma unroll
    for (int k = 0; k < 4; ++k) {
        int t = tid + k * 256;
        int tagt = tg[t];
        float m = mk[t];
        acc += em[((size_t)b * CRF_S + t) * CRF_T + tagt] * m;   // emission at tag
        if (t >= 1) acc += trans[tg[t - 1] * CRF_T + tagt] * m;  // transition score
    }
    if (tid == 0) {
        acc += startT[tg[0]];
        acc += endT[tg[CRF_S - 1]] * mk[CRF_S - 1];
    }
#pragma unroll
    for (int d = 1; d < 64; d <<= 1) acc += __shfl_xor(acc, d);
    __shared__ float r4[4];
    if ((tid & 63) == 0) r4[tid >> 6] = acc;
    __syncthreads();
    if (tid == 0) {
        float tot = (r4[0] + r4[1]) + (r4[2] + r4[3]);
        atomicAdd(out, -tot * (1.0f / CRF_B));
    }
}

// ---------------------------------------------------------------------------
// Kernel 2: scaled linear-domain forward recursion + fused log-softmax
// denominator sum.  One block per batch, 256 threads (4 waves).
//
// Thread mapping: lane l in wave w;  r = l>>3 (row group, 16 i's),
// gl = l&7, g = w*8+gl (column group, 4 j's).  exp(trans) tile in 64 VGPRs.
// One __syncthreads per step (double-buffered A + pipelined c/esum reduction).
// ---------------------------------------------------------------------------
__global__ __launch_bounds__(256) void crf_fwd_kernel(
    const float* __restrict__ em, const float* __restrict__ mask,
    const float* __restrict__ startT, const float* __restrict__ endT,
    const float* __restrict__ trans, float* __restrict__ out)
{
    const int b = blockIdx.x;
    const int tid = threadIdx.x;
    const int w = tid >> 6;
    const int l = tid & 63;
    const int r = l >> 3;
    const int gl = l & 7;
    const int g = w * 8 + gl;
    const int j0 = g * 4;        // this thread's 4 columns
    const int i0 = r * 16;       // this thread's 16 rows
    const int r2 = r >> 1;       // bank-swizzle phase

    __shared__ float Abuf[2][128];
    __shared__ float2 parts[2][4];   // per-wave (c_partial, esum_partial)
    __shared__ float red[8];

    // E[c][k] = exp(trans[i][j0+c]), i ordered with per-thread k-swizzle so the
    // per-step ds_read_b128 of A hits all 32 banks (r-groups offset by r>>1).
    float E[4][16];
#pragma unroll
    for (int kk = 0; kk < 4; ++kk) {
        const int kphys = (kk + r2) & 3;
#pragma unroll
        for (int m = 0; m < 4; ++m) {
            const int i = i0 + 4 * kphys + m;
            float4 t4 = *(const float4*)&trans[i * CRF_T + j0];
            E[0][4 * kk + m] = __expf(t4.x);
            E[1][4 * kk + m] = __expf(t4.y);
            E[2][4 * kk + m] = __expf(t4.z);
            E[3][4 * kk + m] = __expf(t4.w);
        }
    }

    const float* emb = em + (size_t)b * CRF_S * CRF_T + j0;
    const float* mkb = mask + (size_t)b * CRF_S;

    float logZ = 0.f;   // sum log c_t, t = 0..S-2   (forward normalizers)
    float S2 = 0.f;     // sum_t log(sum_j exp(em_tj)) * m_t  (gold denominator)

    float4 embA[4], embB[4];
#pragma unroll
    for (int k = 0; k < 4; ++k) embA[k] = *(const float4*)(emb + (size_t)k * CRF_T);

    auto STEP = [&](int t, float4 emv) {
        const int rb = (t & 1) ^ 1;  // read buffer (written at t-1)
        const int wb = t & 1;        // write buffer
        float rc;
        if (t > 0) {
            // pipelined: consume last step's scale + esum reductions
            float2 p0 = parts[rb][0], p1 = parts[rb][1], p2 = parts[rb][2], p3 = parts[rb][3];
            float c  = (p0.x + p1.x) + (p2.x + p3.x);
            float es = (p0.y + p1.y) + (p2.y + p3.y);
            rc = __builtin_amdgcn_rcpf(c);
            logZ += __logf(c);
            S2 += __logf(es) * mkb[t - 1];
        } else {
            rc = 1.f;
        }

        float d0, d1, d2, d3;
        if (t > 0) {
            d0 = d1 = d2 = d3 = 0.f;
#pragma unroll
            for (int kk = 0; kk < 4; ++kk) {
                const int kphys = (kk + r2) & 3;
                float4 av = *(const float4*)&Abuf[rb][i0 + 4 * kphys];
                const float aval[4] = {av.x, av.y, av.z, av.w};
#pragma unroll
                for (int m = 0; m < 4; ++m) {
                    d0 = fmaf(aval[m], E[0][4 * kk + m], d0);
                    d1 = fmaf(aval[m], E[1][4 * kk + m], d1);
                    d2 = fmaf(aval[m], E[2][4 * kk + m], d2);
                    d3 = fmaf(aval[m], E[3][4 * kk + m], d3);
                }
            }
            // combine the 8 row-group partials (xor over r bits: 8,16,32)
#pragma unroll
            for (int dd = 8; dd <= 32; dd <<= 1) {
                d0 += __shfl_xor(d0, dd);
                d1 += __shfl_xor(d1, dd);
                d2 += __shfl_xor(d2, dd);
                d3 += __shfl_xor(d3, dd);
            }
        } else {
            // t == 0: alpha0 = start + em0  =>  dot := exp(start)
            float4 s4 = *(const float4*)&startT[j0];
            d0 = __expf(s4.x); d1 = __expf(s4.y); d2 = __expf(s4.z); d3 = __expf(s4.w);
        }

        float e0 = __expf(emv.x), e1 = __expf(emv.y), e2 = __expf(emv.z), e3 = __expf(emv.w);
        float a0 = e0 * rc * d0;
        float a1 = e1 * rc * d1;
        float a2 = e2 * rc * d2;
        float a3 = e3 * rc * d3;
        if (r == 0) *(float4*)&Abuf[wb][j0] = make_float4(a0, a1, a2, a3);

        // per-wave partial reductions of c_t and esum_t (xor over gl bits: 1,2,4)
        float csum = (a0 + a1) + (a2 + a3);
        float esum = (e0 + e1) + (e2 + e3);
#pragma unroll
        for (int dd = 1; dd <= 4; dd <<= 1) {
            csum += __shfl_xor(csum, dd);
            esum += __shfl_xor(esum, dd);
        }
        if (l == 0) parts[wb][w] = make_float2(csum, esum);
        __syncthreads();
    };

    for (int c2 = 0; c2 < 128; ++c2) {
        const int t0 = c2 * 8;
#pragma unroll
        for (int k = 0; k < 4; ++k)
            embB[k] = *(const float4*)(emb + (size_t)(t0 + 4 + k) * CRF_T);
#pragma unroll
        for (int k = 0; k < 4; ++k) STEP(t0 + k, embA[k]);
        if (c2 < 127) {
#pragma unroll
            for (int k = 0; k < 4; ++k)
                embA[k] = *(const float4*)(emb + (size_t)(t0 + 8 + k) * CRF_T);
        }
#pragma unroll
        for (int k = 0; k < 4; ++k) STEP(t0 + 4 + k, embB[k]);
    }

    // ---- finale (A~_{S-1} in Abuf[1], c_{S-1}/esum_{S-1} in parts[1]) ----
    const float mlast = mkb[CRF_S - 1];
    {
        float2 p0 = parts[1][0], p1 = parts[1][1], p2 = parts[1][2], p3 = parts[1][3];
        float es = (p0.y + p1.y) + (p2.y + p3.y);
        S2 += __logf(es) * mlast;   // last emission's log-softmax denominator
        // NOTE: c_{S-1} is intentionally NOT added to logZ (never used as a normalizer)
    }
    float v = -3.0e38f;
    if (tid < 128)
        v = (__logf(Abuf[1][tid]) + logZ) * mlast + endT[tid];
    float mx = v;
#pragma unroll
    for (int dd = 1; dd < 64; dd <<= 1) mx = fmaxf(mx, __shfl_xor(mx, dd));
    if (l == 0) red[w] = mx;
    __syncthreads();
    mx = fmaxf(fmaxf(red[0], red[1]), fmaxf(red[2], red[3]));
    float ex = (tid < 128) ? __expf(v - mx) : 0.f;
#pragma unroll
    for (int dd = 1; dd < 64; dd <<= 1) ex += __shfl_xor(ex, dd);
    if (l == 0) red[4 + w] = ex;
    __syncthreads();
    if (tid == 0) {
        float sm = (red[4] + red[5]) + (red[6] + red[7]);
        float fwd = mx + __logf(sm);
        atomicAdd(out, (fwd + S2) * (1.0f / CRF_B));
    }
}

// ---------------------------------------------------------------------------
extern "C" void kernel_launch(void* const* d_in, const int* in_sizes, int n_in,
                              void* d_out, int out_size, void* d_ws, size_t ws_size,
                              hipStream_t stream)
{
    const float* em     = (const float*)d_in[0];
    const int*   tags   = (const int*)d_in[1];
    const float* mask   = (const float*)d_in[2];
    const float* startT = (const float*)d_in[3];
    const float* endT   = (const float*)d_in[4];
    const float* trans  = (const float*)d_in[5];
    float* out = (float*)d_out;

    hipMemsetAsync(out, 0, sizeof(float), stream);
    hipLaunchKernelGGL(crf_gold_kernel, dim3(CRF_B), dim3(256), 0, stream,
                       em, tags, mask, startT, endT, trans, out);
    hipLaunchKernelGGL(crf_fwd_kernel, dim3(CRF_B), dim3(256), 0, stream,
                       em, mask, startT, endT, trans, out);
}